// Round 3
// baseline (88.537 us; speedup 1.0000x reference)
//
#include <hip/hip_runtime.h>

#define C_CURV   0.01f
#define SQRT_C   0.1f
#define EPS_W    1e-6f
#define MIN_NORM 1e-10f
#define BALL_EPS 1e-5f

typedef __attribute__((ext_vector_type(2))) float f32x2;
typedef __attribute__((ext_vector_type(4))) float f32x4;

__device__ __forceinline__ float group4_sum(float v) {
    v += __shfl_xor(v, 1, 4);
    v += __shfl_xor(v, 2, 4);
    return v;
}
__device__ __forceinline__ float group8_sum(float v) {
    v += __shfl_xor(v, 1, 8);
    v += __shfl_xor(v, 2, 8);
    v += __shfl_xor(v, 4, 8);
    return v;
}

// K1 (fused): blocks [0, blocksN) do node pre-pass (4 lanes/node),
// blocks [blocksN, ...) do the dst histogram (1 thread/edge).
// cnt[] and gcount are zeroed by a hipMemsetAsync before this kernel.
__global__ __launch_bounds__(256) void fhnn_prep(
        const float* __restrict__ h_hyper,
        const float* __restrict__ loop_weight,
        const int*   __restrict__ dst,
        float* __restrict__ h_tan,
        float* __restrict__ loop_hyp,
        int*   __restrict__ cnt,
        int N, int E, int blocksN) {
    if ((int)blockIdx.x >= blocksN) {
        int e = (blockIdx.x - blocksN) * blockDim.x + threadIdx.x;
        if (e < E) atomicAdd(&cnt[dst[e]], 1);
        return;
    }
    __shared__ float Wl[256];
    Wl[threadIdx.x] = loop_weight[threadIdx.x];
    __syncthreads();

    int gid = blockIdx.x * blockDim.x + threadIdx.x;
    int t = gid >> 2, j = gid & 3;
    if (t >= N) return;

    f32x4 x = ((const f32x4*)h_hyper)[gid];

    float sq  = group4_sum(x.x * x.x + x.y * x.y + x.z * x.z + x.w * x.w);
    float n   = sqrtf(fmaxf(sq, MIN_NORM));
    float scn = SQRT_C * n;
    float z   = fminf(scn, 1.0f - BALL_EPS);          // scn >= 0
    float at  = 0.5f * logf((1.0f + z) / (1.0f - z)); // arctanh(z)
    float s   = at / scn;
    f32x4 ht  = x * s;
    ((f32x4*)h_tan)[gid] = ht;

    // lt[o] = sum_i ht[i] * Wl[i][o], lane j computes o = 4j..4j+3
    f32x4 acc = (f32x4)(0.0f);
    #pragma unroll
    for (int q = 0; q < 4; ++q) {
        float h0 = __shfl(ht.x, q, 4);
        float h1 = __shfl(ht.y, q, 4);
        float h2 = __shfl(ht.z, q, 4);
        float h3 = __shfl(ht.w, q, 4);
        const f32x4* Wrow = (const f32x4*)Wl;
        acc += h0 * Wrow[(4 * q + 0) * 4 + j];
        acc += h1 * Wrow[(4 * q + 1) * 4 + j];
        acc += h2 * Wrow[(4 * q + 2) * 4 + j];
        acc += h3 * Wrow[(4 * q + 3) * 4 + j];
    }
    float sq2  = group4_sum(acc.x * acc.x + acc.y * acc.y + acc.z * acc.z + acc.w * acc.w);
    float n2   = sqrtf(fmaxf(sq2, MIN_NORM));
    float scn2 = SQRT_C * n2;
    float f    = tanhf(scn2) / scn2;
    ((f32x4*)loop_hyp)[gid] = acc * f;
}

// K2: exclusive scan of cnt -> start & cursor. Wave-level scan + one atomic
// base per wave (arrival order => non-monotonic but valid disjoint partition).
__global__ __launch_bounds__(256) void fhnn_scan(
        const int* __restrict__ cnt,
        int* __restrict__ start,
        int* __restrict__ cursor,
        int* __restrict__ gcount,
        int N) {
    int i = blockIdx.x * blockDim.x + threadIdx.x;
    int lane = threadIdx.x & 63;
    int v = (i < N) ? cnt[i] : 0;
    int incl = v;
    #pragma unroll
    for (int d = 1; d < 64; d <<= 1) {
        int up = __shfl_up(incl, d, 64);
        if (lane >= d) incl += up;
    }
    int total = __shfl(incl, 63, 64);
    int base = 0;
    if (lane == 0) base = atomicAdd(gcount, total);
    base = __shfl(base, 0, 64);
    if (i < N) {
        int excl = base + incl - v;
        start[i]  = excl;
        cursor[i] = excl;
    }
}

// K3: per edge, 8 lanes/edge. Compute lam*msg and lam, write to slot
// pos = atomicAdd(&cursor[dst]) -- coalesced 64B+4B stores, 1 atomic/edge.
__global__ __launch_bounds__(256) void fhnn_edge(
        const float* __restrict__ h_tan,
        const float* __restrict__ rel_weight,
        const float* __restrict__ rel_emb,
        const int*   __restrict__ src,
        const int*   __restrict__ dst,
        const int*   __restrict__ etype,
        int*   __restrict__ cursor,
        float* __restrict__ lammsg,   // [E][16]
        float* __restrict__ lamarr,   // [E]
        int E) {
    int gid = blockIdx.x * blockDim.x + threadIdx.x;
    int e = gid >> 3, j = gid & 7;
    if (e >= E) return;

    int s = src[e], t = dst[e], r = etype[e];
    f32x2 h = ((const f32x2*)h_tan)[s * 8 + j];
    const float* W = rel_weight + (size_t)r * 256;

    f32x2 acc = (f32x2)(0.0f);
    #pragma unroll
    for (int q = 0; q < 8; ++q) {
        float hx = __shfl(h.x, q, 8);
        float hy = __shfl(h.y, q, 8);
        f32x2 w0 = *(const f32x2*)(W + (2 * q + 0) * 16 + 2 * j);
        f32x2 w1 = *(const f32x2*)(W + (2 * q + 1) * 16 + 2 * j);
        acc += hx * w0;
        acc += hy * w1;
    }
    f32x2 v = acc + ((const f32x2*)rel_emb)[r * 8 + j];

    float sq  = group8_sum(v.x * v.x + v.y * v.y);   // sum(v^2) over 16 comps
    float n   = sqrtf(fmaxf(sq, MIN_NORM));
    float scn = SQRT_C * n;
    float f   = tanhf(scn) / scn;
    float m2  = f * f * sq;                           // sum(msg^2)
    float lam = 2.0f / (1.0f - C_CURV * m2 + EPS_W);

    int pos = 0;
    if (j == 0) pos = atomicAdd(&cursor[t], 1);
    pos = __shfl(pos, 0, 8);

    ((f32x2*)lammsg)[pos * 8 + j] = v * (f * lam);
    if (j == 0) lamarr[pos] = lam;
}

// K4: per node, 4 lanes/node. Gather segment, Einstein midpoint, project,
// Mobius-add with loop_hyp, write out.
__global__ __launch_bounds__(256) void fhnn_reduce(
        const float* __restrict__ lammsg,
        const float* __restrict__ lamarr,
        const int*   __restrict__ cnt,
        const int*   __restrict__ start,
        const float* __restrict__ node_norm,
        const float* __restrict__ loop_hyp,
        float* __restrict__ out,
        int N) {
    int gid = blockIdx.x * blockDim.x + threadIdx.x;
    int t = gid >> 2, j = gid & 3;
    if (t >= N) return;

    int cn = cnt[t];
    int st = start[t];

    f32x4 acc = (f32x4)(0.0f);
    float lsum = 0.0f;
    for (int k = 0; k < cn; ++k) {
        int pos = st + k;
        acc  += ((const f32x4*)lammsg)[pos * 4 + j];
        lsum += lamarr[pos];
    }

    float en = node_norm[t];
    float wsc = en / ((float)cn * en + EPS_W);        // w = en / (norm_sum + EPS)
    f32x4 numer = acc * wsc;
    float denom = wsc * lsum + EPS_W;
    f32x4 x = numer * (1.0f / denom);

    // project_to_ball
    float x2 = group4_sum(x.x * x.x + x.y * x.y + x.z * x.z + x.w * x.w);
    float n  = sqrtf(fmaxf(x2, MIN_NORM));
    const float maxn = (1.0f - BALL_EPS) / SQRT_C;
    float scale = (n > maxn) ? (maxn / n) : 1.0f;
    x *= scale;

    f32x4 y = ((const f32x4*)loop_hyp)[gid];
    float x2p = group4_sum(x.x * x.x + x.y * x.y + x.z * x.z + x.w * x.w);
    float y2  = group4_sum(y.x * y.x + y.y * y.y + y.z * y.z + y.w * y.w);
    float xy  = group4_sum(x.x * y.x + x.y * y.y + x.z * y.z + x.w * y.w);

    float a   = 1.0f + 2.0f * C_CURV * xy + C_CURV * y2;
    float b   = 1.0f - C_CURV * x2p;
    f32x4 num = a * x + b * y;
    float d2  = 1.0f + 2.0f * C_CURV * xy + C_CURV * C_CURV * x2p * y2;
    ((f32x4*)out)[gid] = num * (1.0f / fmaxf(d2, MIN_NORM));
}

extern "C" void kernel_launch(void* const* d_in, const int* in_sizes, int n_in,
                              void* d_out, int out_size, void* d_ws, size_t ws_size,
                              hipStream_t stream) {
    const float* h_hyper     = (const float*)d_in[0];
    const float* node_norm   = (const float*)d_in[1];
    const float* rel_weight  = (const float*)d_in[2];
    const float* loop_weight = (const float*)d_in[3];
    const float* rel_emb     = (const float*)d_in[4];
    const int*   src         = (const int*)d_in[5];
    const int*   dst         = (const int*)d_in[6];
    const int*   etype       = (const int*)d_in[7];

    const int N = in_sizes[1];   // node_norm is [N,1]
    const int E = in_sizes[5];

    char* ws = (char*)d_ws;
    size_t offs = 0;
    auto alloc = [&](size_t bytes) -> void* {
        void* p = ws + offs;
        offs += (bytes + 255) & ~(size_t)255;
        return p;
    };
    float* h_tan    = (float*)alloc((size_t)N * 16 * 4);
    float* loop_hyp = (float*)alloc((size_t)N * 16 * 4);
    float* lammsg   = (float*)alloc((size_t)E * 16 * 4);
    float* lamarr   = (float*)alloc((size_t)E * 4);
    char*  izero    = (char*)alloc(0);                  // start of int region to zero
    int*   cnt      = (int*)alloc((size_t)N * 4);
    int*   start    = (int*)alloc((size_t)N * 4);
    int*   cursor   = (int*)alloc((size_t)N * 4);
    int*   gcount   = (int*)alloc(256);
    size_t izero_bytes = (size_t)((char*)gcount - izero) + 256;

    // zero cnt/start/cursor/gcount (start & cursor get rewritten; harmless)
    hipMemsetAsync(izero, 0, izero_bytes, stream);

    const int threads = 256;
    int blocksN4 = (N * 4 + threads - 1) / threads;               // node work, 4 lanes/node
    int blocksH  = (E + threads - 1) / threads;                   // histogram, 1 thread/edge
    int blocksSc = (N + threads - 1) / threads;                   // scan, 1 thread/elem
    int blocksE8 = (int)(((long long)E * 8 + threads - 1) / threads);

    fhnn_prep<<<blocksN4 + blocksH, threads, 0, stream>>>(
        h_hyper, loop_weight, dst, h_tan, loop_hyp, cnt, N, E, blocksN4);
    fhnn_scan<<<blocksSc, threads, 0, stream>>>(cnt, start, cursor, gcount, N);
    fhnn_edge<<<blocksE8, threads, 0, stream>>>(
        h_tan, rel_weight, rel_emb, src, dst, etype, cursor, lammsg, lamarr, E);
    fhnn_reduce<<<blocksN4, threads, 0, stream>>>(
        lammsg, lamarr, cnt, start, node_norm, loop_hyp, (float*)d_out, N);
}